// Round 4
// baseline (44.914 us; speedup 1.0000x reference)
//
#include <hip/hip_runtime.h>

// ButterflyConv2d: 4 fused grouped-1x1-conv rounds with butterfly perms.
// v3: barrier-free / LDS-free. All 4 rounds close over the 64 channels with
// fixed d3=e (a contiguous channel block), so each thread owns all 64
// channels x 2 pixels in registers. Pure stream: 64 f32x2 loads -> in-register
// 4-round butterfly (wave-uniform weights -> s_loads) -> 64 f32x2 nt stores.
//
// x: [32, 256, 56, 56] f32, w_r: [64, 4, 4] f32, out: [32, 256, 56, 56] f32.
// Channel c = (d3,d2,d1,d0) base-4.

#define HW 3136          // 56*56
#define TILE_PX 512      // 256 threads * 2 px
#define NT 7             // ceil(3136 / 512)

typedef float f32x2 __attribute__((ext_vector_type(2)));

__global__ __launch_bounds__(256, 2)
void butterfly_v3(const float* __restrict__ x,
                  const float* __restrict__ w0,
                  const float* __restrict__ w1,
                  const float* __restrict__ w2,
                  const float* __restrict__ w3,
                  float* __restrict__ out) {
    const int bid  = blockIdx.x;
    const int tile = bid % NT;
    const int rem  = bid / NT;
    const int e    = rem & 3;          // SGPR-uniform
    const int img  = rem >> 2;

    const int p = tile * TILE_PX + 2 * (int)threadIdx.x;
    if (p >= HW) return;               // no LDS/barriers -> early exit is safe

    const int ibase = img * 256 * HW + (e << 6) * HW + p;   // 64-ch block start
    const int obase = img * 256 * HW + p;

    // ---- load all 64 channels (d3=e), 2 px each: fully coalesced f32x2 ----
    f32x2 r[64];
#pragma unroll
    for (int k = 0; k < 64; ++k)
        r[k] = *reinterpret_cast<const f32x2*>(x + ibase + k * HW);

    // ---- round 0: group (e,v,i): r[v,i,o] = sum_j w0[g][o][j] * r[v,i,j] ----
#pragma unroll
    for (int v = 0; v < 4; ++v) {
#pragma unroll
        for (int i = 0; i < 4; ++i) {
            const float* wg = w0 + (((e << 4) | (v << 2) | i) << 4);
            const f32x2 in0 = r[v * 16 + i * 4 + 0];
            const f32x2 in1 = r[v * 16 + i * 4 + 1];
            const f32x2 in2 = r[v * 16 + i * 4 + 2];
            const f32x2 in3 = r[v * 16 + i * 4 + 3];
#pragma unroll
            for (int o = 0; o < 4; ++o)
                r[v * 16 + i * 4 + o] =
                    wg[o * 4 + 0] * in0 + wg[o * 4 + 1] * in1 +
                    wg[o * 4 + 2] * in2 + wg[o * 4 + 3] * in3;
        }
    }

    // ---- round 1 (perm0 = swap d1,d0), per set v:
    //      b1[d1,o] = sum_i w1[(e,v,d1)][o][i] * r[v,i,d1]; write back ----
#pragma unroll
    for (int v = 0; v < 4; ++v) {
        f32x2 t16[16];
#pragma unroll
        for (int d1 = 0; d1 < 4; ++d1) {
            const float* wg = w1 + (((e << 4) | (v << 2) | d1) << 4);
#pragma unroll
            for (int o = 0; o < 4; ++o)
                t16[d1 * 4 + o] =
                    wg[o * 4 + 0] * r[v * 16 + 0 * 4 + d1] +
                    wg[o * 4 + 1] * r[v * 16 + 1 * 4 + d1] +
                    wg[o * 4 + 2] * r[v * 16 + 2 * 4 + d1] +
                    wg[o * 4 + 3] * r[v * 16 + 3 * 4 + d1];
        }
#pragma unroll
        for (int k = 0; k < 16; ++k) r[v * 16 + k] = t16[k];
    }
    // now r[v*16 + d1*4 + o] holds round-1 output channel (e, v, d1, o)

    // ---- rounds 2+3 per set (e,f); store outputs immediately ----
#pragma unroll
    for (int f = 0; f < 4; ++f) {
        // round 2: b2[i,o] = sum_i2 w2[(e,f,i)][o][i2] * r[i,i2,f]
        f32x2 b2[16];
#pragma unroll
        for (int i = 0; i < 4; ++i) {
            const float* wg = w2 + (((e << 4) | (f << 2) | i) << 4);
#pragma unroll
            for (int o = 0; o < 4; ++o)
                b2[i * 4 + o] =
                    wg[o * 4 + 0] * r[i * 16 + 0 * 4 + f] +
                    wg[o * 4 + 1] * r[i * 16 + 1 * 4 + f] +
                    wg[o * 4 + 2] * r[i * 16 + 2 * 4 + f] +
                    wg[o * 4 + 3] * r[i * 16 + 3 * 4 + f];
        }
        // round 3: out chan (g2,e,f,o) = sum_k w3[(g2,e,f)][o][k] * b2[k,g2]
#pragma unroll
        for (int g2 = 0; g2 < 4; ++g2) {
            const float* wg = w3 + (((g2 << 4) | (e << 2) | f) << 4);
#pragma unroll
            for (int o = 0; o < 4; ++o) {
                const f32x2 acc =
                    wg[o * 4 + 0] * b2[0 + g2] + wg[o * 4 + 1] * b2[4 + g2] +
                    wg[o * 4 + 2] * b2[8 + g2] + wg[o * 4 + 3] * b2[12 + g2];
                const int c = (g2 << 6) | (e << 4) | (f << 2) | o;
                __builtin_nontemporal_store(acc,
                    reinterpret_cast<f32x2*>(out + obase + c * HW));
            }
        }
    }
}

extern "C" void kernel_launch(void* const* d_in, const int* in_sizes, int n_in,
                              void* d_out, int out_size, void* d_ws, size_t ws_size,
                              hipStream_t stream) {
    const float* x  = (const float*)d_in[0];
    const float* w0 = (const float*)d_in[1];
    const float* w1 = (const float*)d_in[2];
    const float* w2 = (const float*)d_in[3];
    const float* w3 = (const float*)d_in[4];
    float* out = (float*)d_out;

    dim3 grid(32 * 4 * NT);   // (img, e, tile) = 896 blocks
    dim3 block(256);
    butterfly_v3<<<grid, block, 0, stream>>>(x, w0, w1, w2, w3, out);
}

// Round 6
// 39.443 us; speedup vs baseline: 1.1387x; 1.1387x over previous
//
#include <hip/hip_runtime.h>

// ButterflyConv2d: 4 fused grouped-1x1-conv rounds with butterfly perms.
// v5: persistent grid-stride version of v2b (copy-like continuous load/store
// interleave). 416 blocks x 4 tiles = 1664 tiles exactly. Raw s_barrier +
// lgkmcnt-only fences (no vmcnt(0) drain) so global stores of tile t overlap
// loads of tile t+1. Math/LDS layout identical to v2b (verified).
//
// x: [32, 256, 56, 56] f32, w_r: [64, 4, 4] f32, out: [32, 256, 56, 56] f32.
// Channel c = (d3,d2,d1,d0) base-4. Stage A (rounds 0+1) per set (u=e, v);
// stage B (rounds 2+3) per set (e,f) reads only stage-A outputs with u=e.
// Block = (img, e, 256-px tile): 4 waves, wave = one set; thread = 4 px.

#define HW 3136          // 56*56
#define TILE_PX 256
#define NTPI 13          // tiles per (img,e)
#define NBLK 416         // persistent blocks; 4 strided tiles each

typedef float f32x4 __attribute__((ext_vector_type(4)));

__device__ __forceinline__ void fma4(f32x4& acc, float s, const f32x4& a) {
    acc = s * a + acc;
}

// LDS-only barrier: waits DS ops, NOT vmem (keeps global loads/stores in
// flight across the barrier — the __syncthreads vmcnt(0) drain is the cost
// we're removing).
__device__ __forceinline__ void lds_bar() {
    __builtin_amdgcn_sched_barrier(0);
    asm volatile("s_waitcnt lgkmcnt(0)" ::: "memory");
    __builtin_amdgcn_s_barrier();
    __builtin_amdgcn_sched_barrier(0);
}

__global__ __launch_bounds__(256, 2)
void butterfly_v5(const float* __restrict__ x,
                  const float* __restrict__ w0,
                  const float* __restrict__ w1,
                  const float* __restrict__ w2,
                  const float* __restrict__ w3,
                  float* __restrict__ out) {
    __shared__ float buf[64 * TILE_PX];   // 64 KB: [local channel][pixel]

    const int l  = threadIdx.x & 63;                                        // lane
    const int wv = __builtin_amdgcn_readfirstlane((int)(threadIdx.x >> 6)); // 0..3 set

    for (int it = 0; it < 4; ++it) {
        const int t    = (int)blockIdx.x + NBLK * it;   // 0..1663
        const int tile = t % NTPI;
        const int rem  = t / NTPI;
        const int e    = rem & 3;
        const int img  = rem >> 2;

        const int pix  = tile * TILE_PX + 4 * l;
        const bool ok  = pix < HW;
        const int pixc = ok ? pix : 0;             // clamp loads in partial tile
        const int ibase = img * 256 * HW + pixc;
        const int obase = img * 256 * HW + pix;

        // ---- Stage A: rounds 0 & 1, set (u=e, v=wv) ----
        f32x4 xr[16];
#pragma unroll
        for (int i = 0; i < 4; ++i)
#pragma unroll
            for (int j = 0; j < 4; ++j) {
                const int c = (e << 6) | (wv << 4) | (i << 2) | j;
                xr[4 * i + j] = *reinterpret_cast<const f32x4*>(x + ibase + c * HW);
            }

        f32x4 b0[16];
#pragma unroll
        for (int i = 0; i < 4; ++i) {
            const float* wg = w0 + (((e << 4) | (wv << 2) | i) << 4);
#pragma unroll
            for (int o = 0; o < 4; ++o) {
                f32x4 acc = wg[o * 4 + 0] * xr[4 * i + 0];
                fma4(acc, wg[o * 4 + 1], xr[4 * i + 1]);
                fma4(acc, wg[o * 4 + 2], xr[4 * i + 2]);
                fma4(acc, wg[o * 4 + 3], xr[4 * i + 3]);
                b0[4 * i + o] = acc;
            }
        }

        // barrier 1: previous iteration's LDS reads complete before overwrite
        lds_bar();

        // round 1 (perm0 = swap d1,d0) -> LDS at local channel (wv,d1,o)
#pragma unroll
        for (int d1 = 0; d1 < 4; ++d1) {
            const float* wg = w1 + (((e << 4) | (wv << 2) | d1) << 4);
#pragma unroll
            for (int o = 0; o < 4; ++o) {
                f32x4 acc = wg[o * 4 + 0] * b0[0 + d1];
                fma4(acc, wg[o * 4 + 1], b0[4 + d1]);
                fma4(acc, wg[o * 4 + 2], b0[8 + d1]);
                fma4(acc, wg[o * 4 + 3], b0[12 + d1]);
                const int lc = (wv << 4) | (d1 << 2) | o;
                *reinterpret_cast<f32x4*>(buf + lc * TILE_PX + 4 * l) = acc;
            }
        }

        // barrier 2: all LDS writes visible before reads
        lds_bar();

        // ---- Stage B: rounds 2 & 3, set (e, f=wv) ----
        const int f = wv;
        f32x4 yr[16];
#pragma unroll
        for (int i = 0; i < 4; ++i)
#pragma unroll
            for (int i2 = 0; i2 < 4; ++i2) {
                const int lc = (i << 4) | (i2 << 2) | f;
                yr[4 * i + i2] = *reinterpret_cast<const f32x4*>(buf + lc * TILE_PX + 4 * l);
            }

        f32x4 b2[16];
#pragma unroll
        for (int i = 0; i < 4; ++i) {
            const float* wg = w2 + (((e << 4) | (f << 2) | i) << 4);
#pragma unroll
            for (int o = 0; o < 4; ++o) {
                f32x4 acc = wg[o * 4 + 0] * yr[4 * i + 0];
                fma4(acc, wg[o * 4 + 1], yr[4 * i + 1]);
                fma4(acc, wg[o * 4 + 2], yr[4 * i + 2]);
                fma4(acc, wg[o * 4 + 3], yr[4 * i + 3]);
                b2[4 * i + o] = acc;
            }
        }

#pragma unroll
        for (int g2 = 0; g2 < 4; ++g2) {
            const float* wg = w3 + (((g2 << 4) | (e << 2) | f) << 4);
#pragma unroll
            for (int o = 0; o < 4; ++o) {
                f32x4 acc = wg[o * 4 + 0] * b2[0 + g2];
                fma4(acc, wg[o * 4 + 1], b2[4 + g2]);
                fma4(acc, wg[o * 4 + 2], b2[8 + g2]);
                fma4(acc, wg[o * 4 + 3], b2[12 + g2]);
                if (ok) {
                    const int c = (g2 << 6) | (e << 4) | (f << 2) | o;
                    __builtin_nontemporal_store(acc,
                        reinterpret_cast<f32x4*>(out + obase + c * HW));
                }
            }
        }
    }
}

extern "C" void kernel_launch(void* const* d_in, const int* in_sizes, int n_in,
                              void* d_out, int out_size, void* d_ws, size_t ws_size,
                              hipStream_t stream) {
    const float* x  = (const float*)d_in[0];
    const float* w0 = (const float*)d_in[1];
    const float* w1 = (const float*)d_in[2];
    const float* w2 = (const float*)d_in[3];
    const float* w3 = (const float*)d_in[4];
    float* out = (float*)d_out;

    dim3 grid(NBLK);      // persistent: 416 blocks x 4 tiles = 1664 tiles
    dim3 block(256);      // 4 waves: one 16-channel set per wave
    butterfly_v5<<<grid, block, 0, stream>>>(x, w0, w1, w2, w3, out);
}